// Round 5
// baseline (110.462 us; speedup 1.0000x reference)
//
#include <hip/hip_runtime.h>
#include <hip/hip_bf16.h>
#include <math.h>

#define HH 192
#define WW 192
#define NPIX (HH * WW)
#define SCALE 0.25f   // head_dim(16)^-0.5

// attention tile: 8 rows x 4 cols, halo 14 x 10 = 140 pixels
#define THY 8
#define THX 4
#define HLY 14
#define HLX 10
#define NH  (HLY * HLX)          // 140
#define REG (NH * 8 + 4)         // 1124 dwords; 1124 mod 32 = 4 -> head regions
                                 // offset by 4 banks (min conflict for stride-8)

static __device__ __forceinline__ float blo(unsigned int w) { return __uint_as_float(w << 16); }
static __device__ __forceinline__ float bhi(unsigned int w) { return __uint_as_float(w & 0xffff0000u); }

static __device__ __forceinline__ unsigned int pack_bf16(float a, float b)
{
    __hip_bfloat16 lo = __float2bfloat16(a);
    __hip_bfloat16 hi = __float2bfloat16(b);
    unsigned short ul, uh;
    __builtin_memcpy(&ul, &lo, 2);
    __builtin_memcpy(&uh, &hi, 2);
    return ((unsigned int)uh << 16) | ul;
}

// ---------------------------------------------------------------------------
// Kernel 1: fused Q/K/V projection, no LDS, no barriers.
// x [C=64][NPIX] f32 -> q,k,v bf16-packed [NPIX][32 dwords] (dword cp holds
// couts 2cp,2cp+1). Thread = (cout-pair cp = t&31, pixel-group pg = t>>5).
// Block covers 16 pixels (2 px/thread); 2304 blocks -> 9 blocks/CU.
// All loads/stores naturally coalesced; ~45 VGPR -> full occupancy.
// ---------------------------------------------------------------------------
__global__ __launch_bounds__(256) void qkv_kernel(
    const float* __restrict__ x,
    const float* __restrict__ wq, const float* __restrict__ wk,
    const float* __restrict__ wv,
    unsigned int* __restrict__ qg, unsigned int* __restrict__ kg,
    unsigned int* __restrict__ vg)
{
    const int t = threadIdx.x;
    const int cp = t & 31;                    // cout pair
    const int pg = t >> 5;                    // 0..7
    const int px0 = blockIdx.x * 16 + pg * 2; // 2 pixels per thread

    const float2* wq2 = reinterpret_cast<const float2*>(wq);
    const float2* wk2 = reinterpret_cast<const float2*>(wk);
    const float2* wv2 = reinterpret_cast<const float2*>(wv);

    float aq0x = 0.f, aq0y = 0.f, aq1x = 0.f, aq1y = 0.f;
    float ak0x = 0.f, ak0y = 0.f, ak1x = 0.f, ak1y = 0.f;
    float av0x = 0.f, av0y = 0.f, av1x = 0.f, av1y = 0.f;

    #pragma unroll 4
    for (int cin = 0; cin < 64; ++cin) {
        const float2 xv = *reinterpret_cast<const float2*>(x + (size_t)cin * NPIX + px0);
        const float2 wqv = wq2[cin * 32 + cp];
        const float2 wkv = wk2[cin * 32 + cp];
        const float2 wvv = wv2[cin * 32 + cp];
        aq0x = fmaf(xv.x, wqv.x, aq0x); aq0y = fmaf(xv.x, wqv.y, aq0y);
        aq1x = fmaf(xv.y, wqv.x, aq1x); aq1y = fmaf(xv.y, wqv.y, aq1y);
        ak0x = fmaf(xv.x, wkv.x, ak0x); ak0y = fmaf(xv.x, wkv.y, ak0y);
        ak1x = fmaf(xv.y, wkv.x, ak1x); ak1y = fmaf(xv.y, wkv.y, ak1y);
        av0x = fmaf(xv.x, wvv.x, av0x); av0y = fmaf(xv.x, wvv.y, av0y);
        av1x = fmaf(xv.y, wvv.x, av1x); av1y = fmaf(xv.y, wvv.y, av1y);
    }

    qg[(size_t)px0 * 32 + cp]       = pack_bf16(aq0x, aq0y);
    qg[(size_t)(px0 + 1) * 32 + cp] = pack_bf16(aq1x, aq1y);
    kg[(size_t)px0 * 32 + cp]       = pack_bf16(ak0x, ak0y);
    kg[(size_t)(px0 + 1) * 32 + cp] = pack_bf16(ak1x, ak1y);
    vg[(size_t)px0 * 32 + cp]       = pack_bf16(av0x, av0y);
    vg[(size_t)(px0 + 1) * 32 + cp] = pack_bf16(av1x, av1y);
}

// ---------------------------------------------------------------------------
// Kernel 2: tiled neighborhood attention + fused output projection.
// Block = 256 thr: 8x4 pixel tile x 4 heads x 2 neighbor-halves.
// Grid = 1152, XCD-swizzled. LDS 36.5 KB -> 4 blocks/CU resident (~16 waves).
// k,v halo (14x10, bf16, per-head regions) + block-uniform sims staged.
// Halves combined via shfl_xor(1); projection through LDS (pad-33).
// ---------------------------------------------------------------------------
__global__ __launch_bounds__(256) void attn_proj_kernel(
    const unsigned int* __restrict__ qg,
    const unsigned int* __restrict__ kg,
    const unsigned int* __restrict__ vg,
    const float* __restrict__ sims,
    const float* __restrict__ wp,
    float* __restrict__ out)
{
    __shared__ unsigned int smem[8 * REG + NH];   // k[4][REG], v[4][REG], sims[140]

    const int bid = blockIdx.x;
    const int tl = (bid & 7) * 144 + (bid >> 3);  // XCD swizzle (1152 = 8*144)
    const int ty = tl / 48, tx = tl - ty * 48;
    const int Y0 = ty * THY, X0 = tx * THX;
    int hy0 = Y0 - 3; hy0 = hy0 < 0 ? 0 : (hy0 > HH - HLY ? HH - HLY : hy0);
    int hx0 = X0 - 3; hx0 = hx0 < 0 ? 0 : (hx0 > WW - HLX ? WW - HLX : hx0);
    const int t = threadIdx.x;

    // ---- stage k,v halo: 140 rows x 128B = 1120 dwordx4 units per tensor
    #pragma unroll
    for (int i = 0; i < 5; ++i) {
        const int idx = i * 256 + t;
        if (idx < NH * 8) {
            const int hidx = idx >> 3;
            const int u = idx & 7;
            const int r = hidx / HLX;
            const int c = hidx - r * HLX;
            const int np = (hy0 + r) * WW + hx0 + c;
            const uint4 kk = *reinterpret_cast<const uint4*>(kg + (size_t)np * 32 + u * 4);
            const uint4 vv = *reinterpret_cast<const uint4*>(vg + (size_t)np * 32 + u * 4);
            const int h = u >> 1, hf = u & 1;
            unsigned int* dk = smem + h * REG + hidx * 8 + hf * 4;
            *reinterpret_cast<uint4*>(dk) = kk;
            *reinterpret_cast<uint4*>(dk + 4 * REG) = vv;
        }
    }
    if (t < NH) {
        const int r = t / HLX;
        const int c = t - r * HLX;
        const int np = (hy0 + r) * WW + hx0 + c;
        const int sbase = (Y0 >> 4) * 12 + (X0 >> 4);   // block-uniform
        reinterpret_cast<float*>(smem)[8 * REG + t] = sims[np * 144 + sbase];
    }
    __syncthreads();

    // ---- attention: thread = (pixel p, head h, neighbor-half)
    const int p = t >> 3, h = (t >> 1) & 3, half = t & 1;
    const int py = p >> 2, pxq = p & 3;
    const int y = Y0 + py, xq = X0 + pxq;
    int sy = y - 3;  sy = sy < 0 ? 0 : (sy > HH - 7 ? HH - 7 : sy);
    int sx = xq - 3; sx = sx < 0 ? 0 : (sx > WW - 7 ? WW - 7 : sx);
    const int wbase = (sy - hy0) * HLX + (sx - hx0);

    // load + unpack q (bf16) once
    float qv[16];
    {
        const unsigned int* qp = qg + (size_t)(y * WW + xq) * 32 + h * 8;
        const uint4 a = *reinterpret_cast<const uint4*>(qp);
        const uint4 b = *reinterpret_cast<const uint4*>(qp + 4);
        const unsigned int qs[8] = { a.x, a.y, a.z, a.w, b.x, b.y, b.z, b.w };
        #pragma unroll
        for (int e = 0; e < 8; ++e) { qv[2 * e] = blo(qs[e]); qv[2 * e + 1] = bhi(qs[e]); }
    }

    const unsigned int* kreg = smem + h * REG;
    const unsigned int* vreg = kreg + 4 * REG;
    const float* sm = reinterpret_cast<const float*>(smem + 8 * REG);

    float S = 0.f;
    float acc[16];
    #pragma unroll
    for (int d = 0; d < 16; ++d) acc[d] = 0.f;

    #pragma unroll
    for (int i = 0; i < 25; ++i) {
        const int nn = 2 * i + half;
        if (nn < 49) {
            const int ky = (nn * 37) >> 8;        // nn/7 for nn<56
            const int kx = nn - 7 * ky;
            const int hidx = wbase + ky * HLX + kx;

            const uint4 ka = *reinterpret_cast<const uint4*>(kreg + hidx * 8);
            const uint4 k2 = *reinterpret_cast<const uint4*>(kreg + hidx * 8 + 4);
            float d0 = qv[0] * blo(ka.x), d1 = qv[1] * bhi(ka.x);
            float d2 = qv[2] * blo(ka.y), d3 = qv[3] * bhi(ka.y);
            d0 = fmaf(qv[4],  blo(ka.z), d0); d1 = fmaf(qv[5],  bhi(ka.z), d1);
            d2 = fmaf(qv[6],  blo(ka.w), d2); d3 = fmaf(qv[7],  bhi(ka.w), d3);
            d0 = fmaf(qv[8],  blo(k2.x), d0); d1 = fmaf(qv[9],  bhi(k2.x), d1);
            d2 = fmaf(qv[10], blo(k2.y), d2); d3 = fmaf(qv[11], bhi(k2.y), d3);
            d0 = fmaf(qv[12], blo(k2.z), d0); d1 = fmaf(qv[13], bhi(k2.z), d1);
            d2 = fmaf(qv[14], blo(k2.w), d2); d3 = fmaf(qv[15], bhi(k2.w), d3);
            const float dot = (d0 + d1) + (d2 + d3);

            const float m = sm[hidx];
            const float pf = __expf(SCALE * dot * m);
            S += pf;
            const float pm = pf * m;

            const uint4 va = *reinterpret_cast<const uint4*>(vreg + hidx * 8);
            const uint4 v2 = *reinterpret_cast<const uint4*>(vreg + hidx * 8 + 4);
            acc[0]  = fmaf(pm, blo(va.x), acc[0]);
            acc[1]  = fmaf(pm, bhi(va.x), acc[1]);
            acc[2]  = fmaf(pm, blo(va.y), acc[2]);
            acc[3]  = fmaf(pm, bhi(va.y), acc[3]);
            acc[4]  = fmaf(pm, blo(va.z), acc[4]);
            acc[5]  = fmaf(pm, bhi(va.z), acc[5]);
            acc[6]  = fmaf(pm, blo(va.w), acc[6]);
            acc[7]  = fmaf(pm, bhi(va.w), acc[7]);
            acc[8]  = fmaf(pm, blo(v2.x), acc[8]);
            acc[9]  = fmaf(pm, bhi(v2.x), acc[9]);
            acc[10] = fmaf(pm, blo(v2.y), acc[10]);
            acc[11] = fmaf(pm, bhi(v2.y), acc[11]);
            acc[12] = fmaf(pm, blo(v2.z), acc[12]);
            acc[13] = fmaf(pm, bhi(v2.z), acc[13]);
            acc[14] = fmaf(pm, blo(v2.w), acc[14]);
            acc[15] = fmaf(pm, bhi(v2.w), acc[15]);
        }
    }

    // combine even/odd neighbor halves (adjacent lanes share (p,h))
    const float S2 = S + __shfl_xor(S, 1, 64);
    float comb[8];
    #pragma unroll
    for (int j = 0; j < 8; ++j) {
        const float a = acc[half * 8 + j];
        comb[j] = a + __shfl_xor(acc[half * 8 + j] + (acc[(1 - half) * 8 + j] - acc[(1 - half) * 8 + j]), 1, 64);
    }
    // NOTE: the line above must exchange the PARTNER's same-cout partials.
    // Lane(half=0) needs partner's acc[0..7]; partner stores them in its own
    // acc[0..7] too (indices are cout-relative) -> simple xor works:
    #pragma unroll
    for (int j = 0; j < 8; ++j) {
        const float mine  = acc[half * 8 + j];
        const float other = __shfl_xor(mine, 1, 64);
        // 'mine' on lane half=0 is couts 0..7? No: acc index IS cout index.
        comb[j] = 0.f; // overwritten below
    }
    // Correct combine: acc[j] is cout j for BOTH halves; each lane keeps the
    // 8 couts it will write (half*8+j) and sums partner's identical-index acc.
    #pragma unroll
    for (int j = 0; j < 8; ++j) {
        const int cidx = half * 8 + j;
        const float mine = acc[cidx];
        // partner's acc[cidx]: partner computed the SAME cout set, different
        // neighbors -> shfl of acc[cidx] needs same register on both lanes.
        // cidx differs per lane (half differs) -> exchange both ranges:
        comb[j] = mine;
    }
    {
        float lo[8], hi[8];
        #pragma unroll
        for (int j = 0; j < 8; ++j) { lo[j] = acc[j]; hi[j] = acc[8 + j]; }
        #pragma unroll
        for (int j = 0; j < 8; ++j) {
            lo[j] += __shfl_xor(lo[j], 1, 64);
            hi[j] += __shfl_xor(hi[j], 1, 64);
        }
        #pragma unroll
        for (int j = 0; j < 8; ++j) comb[j] = (half == 0) ? lo[j] : hi[j];
    }
    const float inv = 1.f / S2;

    // ---- fused projection through LDS (attn-out transposed, pad 33)
    __syncthreads();                   // all k/v/sims LDS reads done
    float* os = reinterpret_cast<float*>(smem);   // [64 cout][33]
    #pragma unroll
    for (int jj = 0; jj < 8; ++jj)
        os[(h * 16 + half * 8 + jj) * 33 + p] = comb[jj] * inv;
    __syncthreads();

    const int pix2 = t & 31;
    const int cg = t >> 5;            // 0..7 (8 couts each; two groups per wave)
    float o2[8];
    #pragma unroll
    for (int cc = 0; cc < 8; ++cc) o2[cc] = 0.f;

    const float4* wp4 = reinterpret_cast<const float4*>(wp);
    for (int cin = 0; cin < 64; ++cin) {
        const float xv = os[cin * 33 + pix2];
        const float4 wa = wp4[cin * 16 + cg * 2];
        const float4 wb = wp4[cin * 16 + cg * 2 + 1];
        o2[0] = fmaf(xv, wa.x, o2[0]);
        o2[1] = fmaf(xv, wa.y, o2[1]);
        o2[2] = fmaf(xv, wa.z, o2[2]);
        o2[3] = fmaf(xv, wa.w, o2[3]);
        o2[4] = fmaf(xv, wb.x, o2[4]);
        o2[5] = fmaf(xv, wb.y, o2[5]);
        o2[6] = fmaf(xv, wb.z, o2[6]);
        o2[7] = fmaf(xv, wb.w, o2[7]);
    }

    const int gy = Y0 + (pix2 >> 2), gx = X0 + (pix2 & 3);
    #pragma unroll
    for (int cc = 0; cc < 8; ++cc)
        out[(size_t)(cg * 8 + cc) * NPIX + gy * WW + gx] = o2[cc];
}

// ---------------------------------------------------------------------------
extern "C" void kernel_launch(void* const* d_in, const int* in_sizes, int n_in,
                              void* d_out, int out_size, void* d_ws, size_t ws_size,
                              hipStream_t stream)
{
    const float* x    = (const float*)d_in[0];
    const float* sims = (const float*)d_in[1];
    const float* wq   = (const float*)d_in[2];
    const float* wk   = (const float*)d_in[3];
    const float* wv   = (const float*)d_in[4];
    const float* wp   = (const float*)d_in[5];
    float* out = (float*)d_out;

    unsigned int* qg = (unsigned int*)d_ws;            // bf16x2 [NPIX][32]
    unsigned int* kg = qg + (size_t)NPIX * 32;
    unsigned int* vg = kg + (size_t)NPIX * 32;

    qkv_kernel<<<NPIX / 16, 256, 0, stream>>>(x, wq, wk, wv, qg, kg, vg);
    attn_proj_kernel<<<1152, 256, 0, stream>>>(qg, kg, vg, sims, wp, out);
}

// Round 6
// 108.836 us; speedup vs baseline: 1.0149x; 1.0149x over previous
//
#include <hip/hip_runtime.h>
#include <hip/hip_bf16.h>
#include <math.h>

#define HH 192
#define WW 192
#define NPIX (HH * WW)
#define SCALE 0.25f          // head_dim(16)^-0.5
#define REG 1572             // per-head k/v LDS region: 196 px * 8 dw + 4 pad
                             // (1572 mod 32 = 4 -> head regions bank-interleave)

typedef __attribute__((ext_vector_type(8))) short bf16x8;
typedef __attribute__((ext_vector_type(4))) float f32x4;

static __device__ __forceinline__ float blo(unsigned int w) { return __uint_as_float(w << 16); }
static __device__ __forceinline__ float bhi(unsigned int w) { return __uint_as_float(w & 0xffff0000u); }

static __device__ __forceinline__ short bf16s(float f)
{
    __hip_bfloat16 h = __float2bfloat16(f);
    short s; __builtin_memcpy(&s, &h, 2); return s;
}

static __device__ __forceinline__ unsigned int pack_bf16(float a, float b)
{
    unsigned short ul = (unsigned short)bf16s(a);
    unsigned short uh = (unsigned short)bf16s(b);
    return ((unsigned int)uh << 16) | ul;
}

// ---------------------------------------------------------------------------
// Kernel 1: Q/K/V projection via MFMA.
// x [64 cin][NPIX] f32 -> q,k,v bf16-packed [NPIX][32 dw] (dw d = couts 2d,2d+1).
// Block = 256 thr / 4 waves, 64-pixel tile, N = 192 (q|k|v concatenated).
// LDS: xT [64 px][72] bf16 (A), wT [192 n][72] bf16 (B, transposed+converted).
// Wave w = M-tile (16 px); 12 N-tiles x K-steps(2) accumulate; D packed via
// shfl_xor(1) into bf16-pair dwords (D: col=lane&15, row=(lane>>4)*4+reg).
// ---------------------------------------------------------------------------
__global__ __launch_bounds__(256, 4) void qkv_mfma(
    const float* __restrict__ x,
    const float* __restrict__ wq, const float* __restrict__ wk,
    const float* __restrict__ wv,
    unsigned int* __restrict__ qg, unsigned int* __restrict__ kg,
    unsigned int* __restrict__ vg)
{
    __shared__ short lds[(64 + 192) * 72];   // xT then wT
    short* xT = lds;
    short* wT = lds + 64 * 72;
    const int t = threadIdx.x;
    const int px0 = blockIdx.x * 64;

    // stage xT: coalesced f32 reads (64 px per cin row), bf16 convert, transpose
    #pragma unroll
    for (int r = 0; r < 16; ++r) {
        const int idx = r * 256 + t;          // 0..4095
        const int cin = idx >> 6, pxl = idx & 63;
        xT[pxl * 72 + cin] = bf16s(x[(size_t)cin * NPIX + px0 + pxl]);
    }
    // stage wT for all 3 matrices: w[k][n] f32 -> wT[n][k] bf16
    #pragma unroll
    for (int m = 0; m < 3; ++m) {
        const float* ws = (m == 0) ? wq : (m == 1) ? wk : wv;
        #pragma unroll
        for (int r = 0; r < 16; ++r) {
            const int idx = r * 256 + t;      // 0..4095
            const int k = idx >> 6, n = idx & 63;
            wT[(m * 64 + n) * 72 + k] = bf16s(ws[k * 64 + n]);
        }
    }
    __syncthreads();

    const int lane = t & 63;
    const int wid  = t >> 6;                  // M-tile (16 px)
    const int l15  = lane & 15;               // A-row / B-col / D-col
    const int kg4  = lane >> 4;               // K-group (8 elems) / D-row-group

    f32x4 acc[12];
    #pragma unroll
    for (int nt = 0; nt < 12; ++nt) acc[nt] = (f32x4){0.f, 0.f, 0.f, 0.f};

    #pragma unroll
    for (int ks = 0; ks < 2; ++ks) {
        const bf16x8 a = *reinterpret_cast<const bf16x8*>(
            &xT[(wid * 16 + l15) * 72 + ks * 32 + kg4 * 8]);
        #pragma unroll
        for (int nt = 0; nt < 12; ++nt) {
            const bf16x8 b = *reinterpret_cast<const bf16x8*>(
                &wT[(nt * 16 + l15) * 72 + ks * 32 + kg4 * 8]);
            acc[nt] = __builtin_amdgcn_mfma_f32_16x16x32_bf16(a, b, acc[nt], 0, 0, 0);
        }
    }

    // pack D to bf16 pairs: lane even holds n, partner lane holds n+1
    #pragma unroll
    for (int nt = 0; nt < 12; ++nt) {
        unsigned int* dst = (nt < 4) ? qg : (nt < 8) ? kg : vg;
        const int dwb = (nt & 3) * 8 + (l15 >> 1);
        #pragma unroll
        for (int r = 0; r < 4; ++r) {
            const float val = acc[nt][r];
            const float par = __shfl_xor(val, 1, 64);
            if (!(lane & 1)) {
                const int px = px0 + wid * 16 + kg4 * 4 + r;
                dst[(size_t)px * 32 + dwb] = pack_bf16(val, par);
            }
        }
    }
}

// ---------------------------------------------------------------------------
// Kernel 2: tiled neighborhood attention (no projection).
// Block = 256 thr: 8x8 pixel tile x 2 heads x 2 neighbor-halves.
// Grid = 1152 (= 576 tiles x 2 head-pairs), XCD-swizzled; LDS 26 KB ->
// 4+ blocks/CU resident. k,v halo (14x14, bf16, per-head regions spaced
// REG=4 mod 32 -> bank-interleaved) + block-uniform sims staged.
// Output: attn-out bf16-packed [NPIX][32 dw].
// ---------------------------------------------------------------------------
__global__ __launch_bounds__(256, 4) void attn_kernel(
    const unsigned int* __restrict__ qg,
    const unsigned int* __restrict__ kg,
    const unsigned int* __restrict__ vg,
    const float* __restrict__ sims,
    unsigned int* __restrict__ aout)
{
    __shared__ unsigned int smem[4 * REG + 196];  // k[2][REG], v[2][REG], sims

    const int bid = blockIdx.x;
    const int swz = (bid & 7) * 144 + (bid >> 3); // 1152 = 8*144, bijective
    const int tile = swz >> 1, hp = swz & 1;      // head-pair 0/1
    const int ty = tile / 24, tx = tile - ty * 24;
    const int Y0 = ty * 8, X0 = tx * 8;
    int hy0 = Y0 - 3; hy0 = hy0 < 0 ? 0 : (hy0 > HH - 14 ? HH - 14 : hy0);
    int hx0 = X0 - 3; hx0 = hx0 < 0 ? 0 : (hx0 > WW - 14 ? WW - 14 : hx0);
    const int t = threadIdx.x;

    // ---- stage k,v halo: 196 px x (2 heads x 2 half-rows) = 784 uint4 units
    #pragma unroll
    for (int i = 0; i < 4; ++i) {
        const int idx = i * 256 + t;
        if (idx < 784) {
            const int hidx = idx >> 2, u = idx & 3;
            const int r = hidx / 14, c = hidx - r * 14;
            const int np = (hy0 + r) * WW + hx0 + c;
            const int hl = u >> 1, hf = u & 1;
            const size_t src = (size_t)np * 32 + (hp * 2 + hl) * 8 + hf * 4;
            const uint4 kk = *reinterpret_cast<const uint4*>(kg + src);
            const uint4 vv = *reinterpret_cast<const uint4*>(vg + src);
            unsigned int* dk = smem + hl * REG + hidx * 8 + hf * 4;
            *reinterpret_cast<uint4*>(dk) = kk;
            *reinterpret_cast<uint4*>(dk + 2 * REG) = vv;
        }
    }
    if (t < 196) {
        const int r = t / 14, c = t - r * 14;
        const int np = (hy0 + r) * WW + hx0 + c;
        const int sbase = (Y0 >> 4) * 12 + (X0 >> 4);   // block-uniform
        reinterpret_cast<float*>(smem)[4 * REG + t] = sims[np * 144 + sbase];
    }
    __syncthreads();

    // ---- attention: thread = (pixel, head-local, neighbor-half)
    const int p = t >> 2, hl = (t >> 1) & 1, half = t & 1;
    const int h = hp * 2 + hl;
    const int py = p >> 3, pxq = p & 7;
    const int y = Y0 + py, xq = X0 + pxq;
    int sy = y - 3;  sy = sy < 0 ? 0 : (sy > HH - 7 ? HH - 7 : sy);
    int sx = xq - 3; sx = sx < 0 ? 0 : (sx > WW - 7 ? WW - 7 : sx);
    const int wbase = (sy - hy0) * 14 + (sx - hx0);

    float qv[16];
    {
        const unsigned int* qp = qg + (size_t)(y * WW + xq) * 32 + h * 8;
        const uint4 a = *reinterpret_cast<const uint4*>(qp);
        const uint4 b = *reinterpret_cast<const uint4*>(qp + 4);
        const unsigned int qs[8] = { a.x, a.y, a.z, a.w, b.x, b.y, b.z, b.w };
        #pragma unroll
        for (int e = 0; e < 8; ++e) { qv[2 * e] = blo(qs[e]); qv[2 * e + 1] = bhi(qs[e]); }
    }

    const unsigned int* kreg = smem + hl * REG;
    const unsigned int* vreg = smem + (2 + hl) * REG;
    const float* sm = reinterpret_cast<const float*>(smem + 4 * REG);

    float S = 0.f;
    float acc[16];
    #pragma unroll
    for (int d = 0; d < 16; ++d) acc[d] = 0.f;

    #pragma unroll
    for (int i = 0; i < 25; ++i) {
        const int nn = 2 * i + half;
        if (nn < 49) {
            const int ky = (nn * 37) >> 8;        // nn/7 for nn<56
            const int kx = nn - 7 * ky;
            const int hidx = wbase + ky * 14 + kx;

            const uint4 ka = *reinterpret_cast<const uint4*>(kreg + hidx * 8);
            const uint4 k2 = *reinterpret_cast<const uint4*>(kreg + hidx * 8 + 4);
            float d0 = qv[0] * blo(ka.x), d1 = qv[1] * bhi(ka.x);
            float d2 = qv[2] * blo(ka.y), d3 = qv[3] * bhi(ka.y);
            d0 = fmaf(qv[4],  blo(ka.z), d0); d1 = fmaf(qv[5],  bhi(ka.z), d1);
            d2 = fmaf(qv[6],  blo(ka.w), d2); d3 = fmaf(qv[7],  bhi(ka.w), d3);
            d0 = fmaf(qv[8],  blo(k2.x), d0); d1 = fmaf(qv[9],  bhi(k2.x), d1);
            d2 = fmaf(qv[10], blo(k2.y), d2); d3 = fmaf(qv[11], bhi(k2.y), d3);
            d0 = fmaf(qv[12], blo(k2.z), d0); d1 = fmaf(qv[13], bhi(k2.z), d1);
            d2 = fmaf(qv[14], blo(k2.w), d2); d3 = fmaf(qv[15], bhi(k2.w), d3);
            const float dot = (d0 + d1) + (d2 + d3);

            const float m = sm[hidx];
            const float pf = __expf(SCALE * dot * m);
            S += pf;
            const float pm = pf * m;

            const uint4 va = *reinterpret_cast<const uint4*>(vreg + hidx * 8);
            const uint4 v2 = *reinterpret_cast<const uint4*>(vreg + hidx * 8 + 4);
            acc[0]  = fmaf(pm, blo(va.x), acc[0]);
            acc[1]  = fmaf(pm, bhi(va.x), acc[1]);
            acc[2]  = fmaf(pm, blo(va.y), acc[2]);
            acc[3]  = fmaf(pm, bhi(va.y), acc[3]);
            acc[4]  = fmaf(pm, blo(va.z), acc[4]);
            acc[5]  = fmaf(pm, bhi(va.z), acc[5]);
            acc[6]  = fmaf(pm, blo(va.w), acc[6]);
            acc[7]  = fmaf(pm, bhi(va.w), acc[7]);
            acc[8]  = fmaf(pm, blo(v2.x), acc[8]);
            acc[9]  = fmaf(pm, bhi(v2.x), acc[9]);
            acc[10] = fmaf(pm, blo(v2.y), acc[10]);
            acc[11] = fmaf(pm, bhi(v2.y), acc[11]);
            acc[12] = fmaf(pm, blo(v2.z), acc[12]);
            acc[13] = fmaf(pm, bhi(v2.z), acc[13]);
            acc[14] = fmaf(pm, blo(v2.w), acc[14]);
            acc[15] = fmaf(pm, bhi(v2.w), acc[15]);
        }
    }

    // combine even/odd neighbor halves (adjacent lanes share (p,h))
    const float S2 = S + __shfl_xor(S, 1, 64);
    float lo[8], hi[8];
    #pragma unroll
    for (int j = 0; j < 8; ++j) { lo[j] = acc[j]; hi[j] = acc[8 + j]; }
    #pragma unroll
    for (int j = 0; j < 8; ++j) {
        lo[j] += __shfl_xor(lo[j], 1, 64);
        hi[j] += __shfl_xor(hi[j], 1, 64);
    }
    const float inv = 1.f / S2;
    float o[8];
    #pragma unroll
    for (int j = 0; j < 8; ++j) o[j] = ((half == 0) ? lo[j] : hi[j]) * inv;

    // store 8 channels as 4 packed dwords (half0 -> ch0..7, half1 -> ch8..15)
    const uint4 w4 = make_uint4(pack_bf16(o[0], o[1]), pack_bf16(o[2], o[3]),
                                pack_bf16(o[4], o[5]), pack_bf16(o[6], o[7]));
    *reinterpret_cast<uint4*>(aout + (size_t)(y * WW + xq) * 32 + h * 8 + half * 4) = w4;
}

// ---------------------------------------------------------------------------
// Kernel 3: output projection via MFMA + NCHW store.
// A = attn-out bf16 [NPIX][64] (read directly from global as A-fragments),
// B = wp staged transposed bf16 in LDS. D rows are contiguous pixels ->
// float4 stores to out[cout][NPIX]. Block = 512 thr / 8 waves / 128 px.
// ---------------------------------------------------------------------------
__global__ __launch_bounds__(512, 2) void proj_mfma(
    const unsigned int* __restrict__ aout,
    const float* __restrict__ wp,
    float* __restrict__ out)
{
    __shared__ short wT[64 * 72];
    const int t = threadIdx.x;
    const int px0 = blockIdx.x * 128;

    #pragma unroll
    for (int r = 0; r < 8; ++r) {
        const int idx = r * 512 + t;              // 0..4095
        const int k = idx >> 6, n = idx & 63;
        wT[n * 72 + k] = bf16s(wp[k * 64 + n]);
    }
    __syncthreads();

    const int lane = t & 63;
    const int wid  = t >> 6;                      // M-tile (16 px)
    const int l15  = lane & 15;
    const int kg4  = lane >> 4;

    const short* A = reinterpret_cast<const short*>(aout);
    f32x4 acc[4];
    #pragma unroll
    for (int nt = 0; nt < 4; ++nt) acc[nt] = (f32x4){0.f, 0.f, 0.f, 0.f};

    #pragma unroll
    for (int ks = 0; ks < 2; ++ks) {
        const bf16x8 a = *reinterpret_cast<const bf16x8*>(
            &A[(size_t)(px0 + wid * 16 + l15) * 64 + ks * 32 + kg4 * 8]);
        #pragma unroll
        for (int nt = 0; nt < 4; ++nt) {
            const bf16x8 b = *reinterpret_cast<const bf16x8*>(
                &wT[(nt * 16 + l15) * 72 + ks * 32 + kg4 * 8]);
            acc[nt] = __builtin_amdgcn_mfma_f32_16x16x32_bf16(a, b, acc[nt], 0, 0, 0);
        }
    }

    #pragma unroll
    for (int nt = 0; nt < 4; ++nt) {
        const int n = nt * 16 + l15;
        const int px = px0 + wid * 16 + kg4 * 4;  // 4 consecutive rows (pixels)
        *reinterpret_cast<float4*>(out + (size_t)n * NPIX + px) =
            make_float4(acc[nt][0], acc[nt][1], acc[nt][2], acc[nt][3]);
    }
}

// ---------------------------------------------------------------------------
extern "C" void kernel_launch(void* const* d_in, const int* in_sizes, int n_in,
                              void* d_out, int out_size, void* d_ws, size_t ws_size,
                              hipStream_t stream)
{
    const float* x    = (const float*)d_in[0];
    const float* sims = (const float*)d_in[1];
    const float* wq   = (const float*)d_in[2];
    const float* wk   = (const float*)d_in[3];
    const float* wv   = (const float*)d_in[4];
    const float* wp   = (const float*)d_in[5];
    float* out = (float*)d_out;

    unsigned int* qg = (unsigned int*)d_ws;            // bf16x2 [NPIX][32]
    unsigned int* kg = qg + (size_t)NPIX * 32;
    unsigned int* vg = kg + (size_t)NPIX * 32;
    unsigned int* ao = vg + (size_t)NPIX * 32;         // attn-out bf16x2

    qkv_mfma<<<NPIX / 64, 256, 0, stream>>>(x, wq, wk, wv, qg, kg, vg);
    attn_kernel<<<1152, 256, 0, stream>>>(qg, kg, vg, sims, ao);
    proj_mfma<<<NPIX / 128, 512, 0, stream>>>(ao, wp, out);
}

// Round 7
// 46.379 us; speedup vs baseline: 2.3818x; 2.3467x over previous
//
#include <hip/hip_runtime.h>
#include <hip/hip_bf16.h>
#include <math.h>

#define HH 192
#define WW 192
#define NPIX (HH * WW)
#define SCALE 0.25f          // head_dim(16)^-0.5
#define REG 1572             // per-head k/v LDS region: 196 px * 8 dw + 4 pad
                             // (1572 mod 32 = 4 -> head regions bank-interleave)

typedef __attribute__((ext_vector_type(8))) short bf16x8;
typedef __attribute__((ext_vector_type(4))) float f32x4;

static __device__ __forceinline__ float blo(unsigned int w) { return __uint_as_float(w << 16); }
static __device__ __forceinline__ float bhi(unsigned int w) { return __uint_as_float(w & 0xffff0000u); }

static __device__ __forceinline__ short bf16s(float f)
{
    __hip_bfloat16 h = __float2bfloat16(f);
    short s; __builtin_memcpy(&s, &h, 2); return s;
}

static __device__ __forceinline__ unsigned int pack_bf16(float a, float b)
{
    unsigned short ul = (unsigned short)bf16s(a);
    unsigned short uh = (unsigned short)bf16s(b);
    return ((unsigned int)uh << 16) | ul;
}

// ---------------------------------------------------------------------------
// Kernel 1: Q/K/V projection via MFMA. (unchanged from r6 except launch bounds)
// x [64 cin][NPIX] f32 -> q,k,v bf16-packed [NPIX][32 dw].
// ---------------------------------------------------------------------------
__global__ __launch_bounds__(256) void qkv_mfma(
    const float* __restrict__ x,
    const float* __restrict__ wq, const float* __restrict__ wk,
    const float* __restrict__ wv,
    unsigned int* __restrict__ qg, unsigned int* __restrict__ kg,
    unsigned int* __restrict__ vg)
{
    __shared__ short lds[(64 + 192) * 72];   // xT then wT
    short* xT = lds;
    short* wT = lds + 64 * 72;
    const int t = threadIdx.x;
    const int px0 = blockIdx.x * 64;

    #pragma unroll
    for (int r = 0; r < 16; ++r) {
        const int idx = r * 256 + t;          // 0..4095
        const int cin = idx >> 6, pxl = idx & 63;
        xT[pxl * 72 + cin] = bf16s(x[(size_t)cin * NPIX + px0 + pxl]);
    }
    #pragma unroll
    for (int m = 0; m < 3; ++m) {
        const float* ws = (m == 0) ? wq : (m == 1) ? wk : wv;
        #pragma unroll
        for (int r = 0; r < 16; ++r) {
            const int idx = r * 256 + t;      // 0..4095
            const int k = idx >> 6, n = idx & 63;
            wT[(m * 64 + n) * 72 + k] = bf16s(ws[k * 64 + n]);
        }
    }
    __syncthreads();

    const int lane = t & 63;
    const int wid  = t >> 6;                  // M-tile (16 px)
    const int l15  = lane & 15;
    const int kg4  = lane >> 4;

    f32x4 acc[12];
    #pragma unroll
    for (int nt = 0; nt < 12; ++nt) acc[nt] = (f32x4){0.f, 0.f, 0.f, 0.f};

    #pragma unroll
    for (int ks = 0; ks < 2; ++ks) {
        const bf16x8 a = *reinterpret_cast<const bf16x8*>(
            &xT[(wid * 16 + l15) * 72 + ks * 32 + kg4 * 8]);
        #pragma unroll
        for (int nt = 0; nt < 12; ++nt) {
            const bf16x8 b = *reinterpret_cast<const bf16x8*>(
                &wT[(nt * 16 + l15) * 72 + ks * 32 + kg4 * 8]);
            acc[nt] = __builtin_amdgcn_mfma_f32_16x16x32_bf16(a, b, acc[nt], 0, 0, 0);
        }
    }

    #pragma unroll
    for (int nt = 0; nt < 12; ++nt) {
        unsigned int* dst = (nt < 4) ? qg : (nt < 8) ? kg : vg;
        const int dwb = (nt & 3) * 8 + (l15 >> 1);
        #pragma unroll
        for (int r = 0; r < 4; ++r) {
            const float val = acc[nt][r];
            const float par = __shfl_xor(val, 1, 64);
            if (!(lane & 1)) {
                const int px = px0 + wid * 16 + kg4 * 4 + r;
                dst[(size_t)px * 32 + dwb] = pack_bf16(val, par);
            }
        }
    }
}

// one neighborhood step: dot(q,k)*m -> exp -> accumulate into acc/S
#define NBR_STEP(HIDX)                                                        \
    {                                                                         \
        const int hidx_ = (HIDX);                                             \
        const uint4 ka = *reinterpret_cast<const uint4*>(kreg + hidx_ * 8);   \
        const uint4 k2 = *reinterpret_cast<const uint4*>(kreg + hidx_ * 8 + 4);\
        float d0 = qv[0] * blo(ka.x), d1 = qv[1] * bhi(ka.x);                 \
        float d2 = qv[2] * blo(ka.y), d3 = qv[3] * bhi(ka.y);                 \
        d0 = fmaf(qv[4],  blo(ka.z), d0); d1 = fmaf(qv[5],  bhi(ka.z), d1);   \
        d2 = fmaf(qv[6],  blo(ka.w), d2); d3 = fmaf(qv[7],  bhi(ka.w), d3);   \
        d0 = fmaf(qv[8],  blo(k2.x), d0); d1 = fmaf(qv[9],  bhi(k2.x), d1);   \
        d2 = fmaf(qv[10], blo(k2.y), d2); d3 = fmaf(qv[11], bhi(k2.y), d3);   \
        d0 = fmaf(qv[12], blo(k2.z), d0); d1 = fmaf(qv[13], bhi(k2.z), d1);   \
        d2 = fmaf(qv[14], blo(k2.w), d2); d3 = fmaf(qv[15], bhi(k2.w), d3);   \
        const float dot = (d0 + d1) + (d2 + d3);                              \
        const float m = sm[hidx_];                                            \
        const float pf = __expf(SCALE * dot * m);                             \
        S += pf;                                                              \
        const float pm = pf * m;                                              \
        const uint4 va = *reinterpret_cast<const uint4*>(vreg + hidx_ * 8);   \
        const uint4 v2 = *reinterpret_cast<const uint4*>(vreg + hidx_ * 8 + 4);\
        acc[0]  = fmaf(pm, blo(va.x), acc[0]);                                \
        acc[1]  = fmaf(pm, bhi(va.x), acc[1]);                                \
        acc[2]  = fmaf(pm, blo(va.y), acc[2]);                                \
        acc[3]  = fmaf(pm, bhi(va.y), acc[3]);                                \
        acc[4]  = fmaf(pm, blo(va.z), acc[4]);                                \
        acc[5]  = fmaf(pm, bhi(va.z), acc[5]);                                \
        acc[6]  = fmaf(pm, blo(va.w), acc[6]);                                \
        acc[7]  = fmaf(pm, bhi(va.w), acc[7]);                                \
        acc[8]  = fmaf(pm, blo(v2.x), acc[8]);                                \
        acc[9]  = fmaf(pm, bhi(v2.x), acc[9]);                                \
        acc[10] = fmaf(pm, blo(v2.y), acc[10]);                               \
        acc[11] = fmaf(pm, bhi(v2.y), acc[11]);                               \
        acc[12] = fmaf(pm, blo(v2.z), acc[12]);                               \
        acc[13] = fmaf(pm, bhi(v2.z), acc[13]);                               \
        acc[14] = fmaf(pm, blo(v2.w), acc[14]);                               \
        acc[15] = fmaf(pm, bhi(v2.w), acc[15]);                               \
    }

// ---------------------------------------------------------------------------
// Kernel 2: tiled neighborhood attention.
// Block = 256 thr: 8x8 pixel tile x 2 heads x 2 neighbor-halves.
// Grid = 1152 (576 tiles x 2 head-pairs), XCD-swizzled; LDS 26 KB.
// Plain launch bounds: let the allocator take ~100 VGPRs (NO spills).
// ---------------------------------------------------------------------------
__global__ __launch_bounds__(256) void attn_kernel(
    const unsigned int* __restrict__ qg,
    const unsigned int* __restrict__ kg,
    const unsigned int* __restrict__ vg,
    const float* __restrict__ sims,
    unsigned int* __restrict__ aout)
{
    __shared__ unsigned int smem[4 * REG + 196];  // k[2][REG], v[2][REG], sims

    const int bid = blockIdx.x;
    const int swz = (bid & 7) * 144 + (bid >> 3); // 1152 = 8*144, bijective
    const int tile = swz >> 1, hp = swz & 1;      // head-pair 0/1
    const int ty = tile / 24, tx = tile - ty * 24;
    const int Y0 = ty * 8, X0 = tx * 8;
    int hy0 = Y0 - 3; hy0 = hy0 < 0 ? 0 : (hy0 > HH - 14 ? HH - 14 : hy0);
    int hx0 = X0 - 3; hx0 = hx0 < 0 ? 0 : (hx0 > WW - 14 ? WW - 14 : hx0);
    const int t = threadIdx.x;

    // ---- stage k,v halo: 196 px x (2 heads x 2 half-rows) = 784 uint4 units
    #pragma unroll
    for (int i = 0; i < 4; ++i) {
        const int idx = i * 256 + t;
        if (idx < 784) {
            const int hidx = idx >> 2, u = idx & 3;
            const int r = hidx / 14, c = hidx - r * 14;
            const int np = (hy0 + r) * WW + hx0 + c;
            const int hl = u >> 1, hf = u & 1;
            const size_t src = (size_t)np * 32 + (hp * 2 + hl) * 8 + hf * 4;
            const uint4 kk = *reinterpret_cast<const uint4*>(kg + src);
            const uint4 vv = *reinterpret_cast<const uint4*>(vg + src);
            unsigned int* dk = smem + hl * REG + hidx * 8 + hf * 4;
            *reinterpret_cast<uint4*>(dk) = kk;
            *reinterpret_cast<uint4*>(dk + 2 * REG) = vv;
        }
    }
    if (t < 196) {
        const int r = t / 14, c = t - r * 14;
        const int np = (hy0 + r) * WW + hx0 + c;
        const int sbase = (Y0 >> 4) * 12 + (X0 >> 4);   // block-uniform
        reinterpret_cast<float*>(smem)[4 * REG + t] = sims[np * 144 + sbase];
    }
    __syncthreads();

    // ---- attention: thread = (pixel, head-local, neighbor-half)
    const int p = t >> 2, hl = (t >> 1) & 1, half = t & 1;
    const int h = hp * 2 + hl;
    const int py = p >> 3, pxq = p & 7;
    const int y = Y0 + py, xq = X0 + pxq;
    int sy = y - 3;  sy = sy < 0 ? 0 : (sy > HH - 7 ? HH - 7 : sy);
    int sx = xq - 3; sx = sx < 0 ? 0 : (sx > WW - 7 ? WW - 7 : sx);
    const int wbase = (sy - hy0) * 14 + (sx - hx0);

    float qv[16];
    {
        const unsigned int* qp = qg + (size_t)(y * WW + xq) * 32 + h * 8;
        const uint4 a = *reinterpret_cast<const uint4*>(qp);
        const uint4 b = *reinterpret_cast<const uint4*>(qp + 4);
        const unsigned int qs[8] = { a.x, a.y, a.z, a.w, b.x, b.y, b.z, b.w };
        #pragma unroll
        for (int e = 0; e < 8; ++e) { qv[2 * e] = blo(qs[e]); qv[2 * e + 1] = bhi(qs[e]); }
    }

    const unsigned int* kreg = smem + hl * REG;
    const unsigned int* vreg = smem + (2 + hl) * REG;
    const float* sm = reinterpret_cast<const float*>(smem + 4 * REG);

    float S = 0.f;
    float acc[16];
    #pragma unroll
    for (int d = 0; d < 16; ++d) acc[d] = 0.f;

    // neighbors nn = 2*i + half, i = 0..23 unconditional; tail nn=48 (half 0)
    #pragma unroll
    for (int i = 0; i < 24; ++i) {
        const int nn = 2 * i + half;
        const int ky = (nn * 37) >> 8;        // nn/7 for nn<56
        const int kx = nn - 7 * ky;
        NBR_STEP(wbase + ky * 14 + kx);
    }
    if (half == 0) {
        NBR_STEP(wbase + 6 * 14 + 6);         // nn = 48 -> ky=6, kx=6
    }

    // combine even/odd neighbor halves (adjacent lanes share (p,h))
    const float S2 = S + __shfl_xor(S, 1, 64);
    float lo[8], hi[8];
    #pragma unroll
    for (int j = 0; j < 8; ++j) { lo[j] = acc[j]; hi[j] = acc[8 + j]; }
    #pragma unroll
    for (int j = 0; j < 8; ++j) {
        lo[j] += __shfl_xor(lo[j], 1, 64);
        hi[j] += __shfl_xor(hi[j], 1, 64);
    }
    const float inv = 1.f / S2;
    float o[8];
    #pragma unroll
    for (int j = 0; j < 8; ++j) o[j] = ((half == 0) ? lo[j] : hi[j]) * inv;

    const uint4 w4 = make_uint4(pack_bf16(o[0], o[1]), pack_bf16(o[2], o[3]),
                                pack_bf16(o[4], o[5]), pack_bf16(o[6], o[7]));
    *reinterpret_cast<uint4*>(aout + (size_t)(y * WW + xq) * 32 + h * 8 + half * 4) = w4;
}

// ---------------------------------------------------------------------------
// Kernel 3: output projection via MFMA + NCHW store. (unchanged except bounds)
// ---------------------------------------------------------------------------
__global__ __launch_bounds__(512) void proj_mfma(
    const unsigned int* __restrict__ aout,
    const float* __restrict__ wp,
    float* __restrict__ out)
{
    __shared__ short wT[64 * 72];
    const int t = threadIdx.x;
    const int px0 = blockIdx.x * 128;

    #pragma unroll
    for (int r = 0; r < 8; ++r) {
        const int idx = r * 512 + t;              // 0..4095
        const int k = idx >> 6, n = idx & 63;
        wT[n * 72 + k] = bf16s(wp[k * 64 + n]);
    }
    __syncthreads();

    const int lane = t & 63;
    const int wid  = t >> 6;                      // M-tile (16 px)
    const int l15  = lane & 15;
    const int kg4  = lane >> 4;

    const short* A = reinterpret_cast<const short*>(aout);
    f32x4 acc[4];
    #pragma unroll
    for (int nt = 0; nt < 4; ++nt) acc[nt] = (f32x4){0.f, 0.f, 0.f, 0.f};

    #pragma unroll
    for (int ks = 0; ks < 2; ++ks) {
        const bf16x8 a = *reinterpret_cast<const bf16x8*>(
            &A[(size_t)(px0 + wid * 16 + l15) * 64 + ks * 32 + kg4 * 8]);
        #pragma unroll
        for (int nt = 0; nt < 4; ++nt) {
            const bf16x8 b = *reinterpret_cast<const bf16x8*>(
                &wT[(nt * 16 + l15) * 72 + ks * 32 + kg4 * 8]);
            acc[nt] = __builtin_amdgcn_mfma_f32_16x16x32_bf16(a, b, acc[nt], 0, 0, 0);
        }
    }

    #pragma unroll
    for (int nt = 0; nt < 4; ++nt) {
        const int n = nt * 16 + l15;
        const int px = px0 + wid * 16 + kg4 * 4;  // 4 consecutive pixels
        *reinterpret_cast<float4*>(out + (size_t)n * NPIX + px) =
            make_float4(acc[nt][0], acc[nt][1], acc[nt][2], acc[nt][3]);
    }
}

// ---------------------------------------------------------------------------
extern "C" void kernel_launch(void* const* d_in, const int* in_sizes, int n_in,
                              void* d_out, int out_size, void* d_ws, size_t ws_size,
                              hipStream_t stream)
{
    const float* x    = (const float*)d_in[0];
    const float* sims = (const float*)d_in[1];
    const float* wq   = (const float*)d_in[2];
    const float* wk   = (const float*)d_in[3];
    const float* wv   = (const float*)d_in[4];
    const float* wp   = (const float*)d_in[5];
    float* out = (float*)d_out;

    unsigned int* qg = (unsigned int*)d_ws;            // bf16x2 [NPIX][32]
    unsigned int* kg = qg + (size_t)NPIX * 32;
    unsigned int* vg = kg + (size_t)NPIX * 32;
    unsigned int* ao = vg + (size_t)NPIX * 32;         // attn-out bf16x2

    qkv_mfma<<<NPIX / 64, 256, 0, stream>>>(x, wq, wk, wv, qg, kg, vg);
    attn_kernel<<<1152, 256, 0, stream>>>(qg, kg, vg, sims, ao);
    proj_mfma<<<NPIX / 128, 512, 0, stream>>>(ao, wp, out);
}

// Round 8
// 44.915 us; speedup vs baseline: 2.4594x; 1.0326x over previous
//
#include <hip/hip_runtime.h>
#include <hip/hip_bf16.h>
#include <math.h>

#define HH 192
#define WW 192
#define NPIX (HH * WW)
#define SCALE 0.25f          // head_dim(16)^-0.5

// attention tile: 8 rows x 4 cols, all 4 heads; halo 14 x 10 = 140 pixels
#define HLY 14
#define HLX 10
#define NH  (HLY * HLX)      // 140
#define REG2 (NH * 8 + 4)    // 1124 dw; 1124 mod 32 = 4 -> head regions
                             // stagger by 4 banks (r7-proven pattern)

typedef __attribute__((ext_vector_type(8))) short bf16x8;
typedef __attribute__((ext_vector_type(4))) float f32x4;

static __device__ __forceinline__ float blo(unsigned int w) { return __uint_as_float(w << 16); }
static __device__ __forceinline__ float bhi(unsigned int w) { return __uint_as_float(w & 0xffff0000u); }

static __device__ __forceinline__ short bf16s(float f)
{
    __hip_bfloat16 h = __float2bfloat16(f);
    short s; __builtin_memcpy(&s, &h, 2); return s;
}

static __device__ __forceinline__ unsigned int pack_bf16(float a, float b)
{
    unsigned short ul = (unsigned short)bf16s(a);
    unsigned short uh = (unsigned short)bf16s(b);
    return ((unsigned int)uh << 16) | ul;
}

// ---------------------------------------------------------------------------
// Kernel 1: Q/K/V projection via MFMA (unchanged from r7).
// x [64 cin][NPIX] f32 -> q,k,v bf16-packed [NPIX][32 dw].
// ---------------------------------------------------------------------------
__global__ __launch_bounds__(256) void qkv_mfma(
    const float* __restrict__ x,
    const float* __restrict__ wq, const float* __restrict__ wk,
    const float* __restrict__ wv,
    unsigned int* __restrict__ qg, unsigned int* __restrict__ kg,
    unsigned int* __restrict__ vg)
{
    __shared__ short lds[(64 + 192) * 72];   // xT then wT
    short* xT = lds;
    short* wT = lds + 64 * 72;
    const int t = threadIdx.x;
    const int px0 = blockIdx.x * 64;

    #pragma unroll
    for (int r = 0; r < 16; ++r) {
        const int idx = r * 256 + t;          // 0..4095
        const int cin = idx >> 6, pxl = idx & 63;
        xT[pxl * 72 + cin] = bf16s(x[(size_t)cin * NPIX + px0 + pxl]);
    }
    #pragma unroll
    for (int m = 0; m < 3; ++m) {
        const float* ws = (m == 0) ? wq : (m == 1) ? wk : wv;
        #pragma unroll
        for (int r = 0; r < 16; ++r) {
            const int idx = r * 256 + t;      // 0..4095
            const int k = idx >> 6, n = idx & 63;
            wT[(m * 64 + n) * 72 + k] = bf16s(ws[k * 64 + n]);
        }
    }
    __syncthreads();

    const int lane = t & 63;
    const int wid  = t >> 6;                  // M-tile (16 px)
    const int l15  = lane & 15;
    const int kg4  = lane >> 4;

    f32x4 acc[12];
    #pragma unroll
    for (int nt = 0; nt < 12; ++nt) acc[nt] = (f32x4){0.f, 0.f, 0.f, 0.f};

    #pragma unroll
    for (int ks = 0; ks < 2; ++ks) {
        const bf16x8 a = *reinterpret_cast<const bf16x8*>(
            &xT[(wid * 16 + l15) * 72 + ks * 32 + kg4 * 8]);
        #pragma unroll
        for (int nt = 0; nt < 12; ++nt) {
            const bf16x8 b = *reinterpret_cast<const bf16x8*>(
                &wT[(nt * 16 + l15) * 72 + ks * 32 + kg4 * 8]);
            acc[nt] = __builtin_amdgcn_mfma_f32_16x16x32_bf16(a, b, acc[nt], 0, 0, 0);
        }
    }

    #pragma unroll
    for (int nt = 0; nt < 12; ++nt) {
        unsigned int* dst = (nt < 4) ? qg : (nt < 8) ? kg : vg;
        const int dwb = (nt & 3) * 8 + (l15 >> 1);
        #pragma unroll
        for (int r = 0; r < 4; ++r) {
            const float val = acc[nt][r];
            const float par = __shfl_xor(val, 1, 64);
            if (!(lane & 1)) {
                const int px = px0 + wid * 16 + kg4 * 4 + r;
                dst[(size_t)px * 32 + dwb] = pack_bf16(val, par);
            }
        }
    }
}

// one neighborhood step: dot(q,k)*m -> exp -> accumulate into acc/S
#define NBR_STEP(HIDX)                                                        \
    {                                                                         \
        const int hidx_ = (HIDX);                                             \
        const uint4 ka = *reinterpret_cast<const uint4*>(kreg + hidx_ * 8);   \
        const uint4 k2 = *reinterpret_cast<const uint4*>(kreg + hidx_ * 8 + 4);\
        float d0 = qv[0] * blo(ka.x), d1 = qv[1] * bhi(ka.x);                 \
        float d2 = qv[2] * blo(ka.y), d3 = qv[3] * bhi(ka.y);                 \
        d0 = fmaf(qv[4],  blo(ka.z), d0); d1 = fmaf(qv[5],  bhi(ka.z), d1);   \
        d2 = fmaf(qv[6],  blo(ka.w), d2); d3 = fmaf(qv[7],  bhi(ka.w), d3);   \
        d0 = fmaf(qv[8],  blo(k2.x), d0); d1 = fmaf(qv[9],  bhi(k2.x), d1);   \
        d2 = fmaf(qv[10], blo(k2.y), d2); d3 = fmaf(qv[11], bhi(k2.y), d3);   \
        d0 = fmaf(qv[12], blo(k2.z), d0); d1 = fmaf(qv[13], bhi(k2.z), d1);   \
        d2 = fmaf(qv[14], blo(k2.w), d2); d3 = fmaf(qv[15], bhi(k2.w), d3);   \
        const float dot = (d0 + d1) + (d2 + d3);                              \
        const float m = sm[hidx_];                                            \
        const float pf = __expf(SCALE * dot * m);                             \
        S += pf;                                                              \
        const float pm = pf * m;                                              \
        const uint4 va = *reinterpret_cast<const uint4*>(vreg + hidx_ * 8);   \
        const uint4 v2 = *reinterpret_cast<const uint4*>(vreg + hidx_ * 8 + 4);\
        acc[0]  = fmaf(pm, blo(va.x), acc[0]);                                \
        acc[1]  = fmaf(pm, bhi(va.x), acc[1]);                                \
        acc[2]  = fmaf(pm, blo(va.y), acc[2]);                                \
        acc[3]  = fmaf(pm, bhi(va.y), acc[3]);                                \
        acc[4]  = fmaf(pm, blo(va.z), acc[4]);                                \
        acc[5]  = fmaf(pm, bhi(va.z), acc[5]);                                \
        acc[6]  = fmaf(pm, blo(va.w), acc[6]);                                \
        acc[7]  = fmaf(pm, bhi(va.w), acc[7]);                                \
        acc[8]  = fmaf(pm, blo(v2.x), acc[8]);                                \
        acc[9]  = fmaf(pm, bhi(v2.x), acc[9]);                                \
        acc[10] = fmaf(pm, blo(v2.y), acc[10]);                               \
        acc[11] = fmaf(pm, bhi(v2.y), acc[11]);                               \
        acc[12] = fmaf(pm, blo(v2.z), acc[12]);                               \
        acc[13] = fmaf(pm, bhi(v2.z), acc[13]);                               \
        acc[14] = fmaf(pm, blo(v2.w), acc[14]);                               \
        acc[15] = fmaf(pm, bhi(v2.w), acc[15]);                               \
    }

// ---------------------------------------------------------------------------
// Kernel 2: tiled neighborhood attention + fused MFMA output projection.
// Block = 256 thr: 8x4 pixel tile x 4 heads x 2 neighbor-halves.
// Lane map (r7-proven, conflict-free): half=t&1, hl=(t>>1)&1, px=(t>>2)&31,
// head-pair hp=t>>7. Grid 1152, XCD-swizzled. LDS 36.5 KB -> 4 blocks/CU.
// After attention, attn-out bounces through the dead k/v LDS as bf16 A-tile
// and is projected with mfma_16x16x32 (w_proj B-frags read from global),
// stores go straight to NCHW out.
// ---------------------------------------------------------------------------
__global__ __launch_bounds__(256) void attn_proj(
    const unsigned int* __restrict__ qg,
    const unsigned int* __restrict__ kg,
    const unsigned int* __restrict__ vg,
    const float* __restrict__ sims,
    const float* __restrict__ wp,
    float* __restrict__ out)
{
    __shared__ unsigned int smem[8 * REG2 + NH];  // k[4][REG2], v[4][REG2], sims

    const int bid = blockIdx.x;
    const int tl = (bid & 7) * 144 + (bid >> 3);  // XCD swizzle (1152 = 8*144)
    const int ty = tl / 48, tx = tl - ty * 48;
    const int Y0 = ty * 8, X0 = tx * 4;
    int hy0 = Y0 - 3; hy0 = hy0 < 0 ? 0 : (hy0 > HH - HLY ? HH - HLY : hy0);
    int hx0 = X0 - 3; hx0 = hx0 < 0 ? 0 : (hx0 > WW - HLX ? WW - HLX : hx0);
    const int t = threadIdx.x;

    // ---- stage k,v halo: 140 px x 8 uint4 (64 ch) = 1120 units per tensor
    #pragma unroll
    for (int i = 0; i < 5; ++i) {
        const int idx = i * 256 + t;
        if (idx < NH * 8) {
            const int hidx = idx >> 3, u = idx & 7;
            const int r = hidx / HLX, c = hidx - r * HLX;
            const int np = (hy0 + r) * WW + hx0 + c;
            const int h = u >> 1, hf = u & 1;
            const size_t src = (size_t)np * 32 + u * 4;
            const uint4 kk = *reinterpret_cast<const uint4*>(kg + src);
            const uint4 vv = *reinterpret_cast<const uint4*>(vg + src);
            unsigned int* dk = smem + h * REG2 + hidx * 8 + hf * 4;
            *reinterpret_cast<uint4*>(dk) = kk;
            *reinterpret_cast<uint4*>(dk + 4 * REG2) = vv;
        }
    }
    if (t < NH) {
        const int r = t / HLX, c = t - r * HLX;
        const int np = (hy0 + r) * WW + hx0 + c;
        const int sbase = (Y0 >> 4) * 12 + (X0 >> 4);   // block-uniform
        reinterpret_cast<float*>(smem)[8 * REG2 + t] = sims[np * 144 + sbase];
    }
    __syncthreads();

    // ---- attention: thread = (pixel, head, neighbor-half)
    const int half = t & 1, hl = (t >> 1) & 1, p = (t >> 2) & 31, hp = t >> 7;
    const int h = hp * 2 + hl;
    const int py = p >> 2, pxq = p & 3;
    const int y = Y0 + py, xq = X0 + pxq;
    int sy = y - 3;  sy = sy < 0 ? 0 : (sy > HH - 7 ? HH - 7 : sy);
    int sx = xq - 3; sx = sx < 0 ? 0 : (sx > WW - 7 ? WW - 7 : sx);
    const int wbase = (sy - hy0) * HLX + (sx - hx0);

    float qv[16];
    {
        const unsigned int* qp = qg + (size_t)(y * WW + xq) * 32 + h * 8;
        const uint4 a = *reinterpret_cast<const uint4*>(qp);
        const uint4 b = *reinterpret_cast<const uint4*>(qp + 4);
        const unsigned int qs[8] = { a.x, a.y, a.z, a.w, b.x, b.y, b.z, b.w };
        #pragma unroll
        for (int e = 0; e < 8; ++e) { qv[2 * e] = blo(qs[e]); qv[2 * e + 1] = bhi(qs[e]); }
    }

    const unsigned int* kreg = smem + h * REG2;
    const unsigned int* vreg = smem + (4 + h) * REG2;
    const float* sm = reinterpret_cast<const float*>(smem + 8 * REG2);

    float S = 0.f;
    float acc[16];
    #pragma unroll
    for (int d = 0; d < 16; ++d) acc[d] = 0.f;

    // neighbors nn = 2*i + half, i = 0..23 unconditional; tail nn=48 (half 0)
    #pragma unroll
    for (int i = 0; i < 24; ++i) {
        const int nn = 2 * i + half;
        const int ky = (nn * 37) >> 8;        // nn/7 for nn<56
        const int kx = nn - 7 * ky;
        NBR_STEP(wbase + ky * HLX + kx);
    }
    if (half == 0) {
        NBR_STEP(wbase + 6 * HLX + 6);        // nn = 48
    }

    // combine even/odd neighbor halves (adjacent lanes share (p,h))
    const float S2 = S + __shfl_xor(S, 1, 64);
    float lo[8], hi[8];
    #pragma unroll
    for (int j = 0; j < 8; ++j) { lo[j] = acc[j]; hi[j] = acc[8 + j]; }
    #pragma unroll
    for (int j = 0; j < 8; ++j) {
        lo[j] += __shfl_xor(lo[j], 1, 64);
        hi[j] += __shfl_xor(hi[j], 1, 64);
    }
    const float inv = 1.f / S2;
    float o[8];
    #pragma unroll
    for (int j = 0; j < 8; ++j) o[j] = ((half == 0) ? lo[j] : hi[j]) * inv;

    // ---- fused projection: attn-out -> LDS (bf16 A-tile), MFMA with wp
    __syncthreads();                           // all k/v/sims LDS reads done
    {
        // A_lds: [32 px][72 ch-pad] shorts, overlaps dead k region
        short* A_lds = reinterpret_cast<short*>(smem);
        const uint4 w4 = make_uint4(pack_bf16(o[0], o[1]), pack_bf16(o[2], o[3]),
                                    pack_bf16(o[4], o[5]), pack_bf16(o[6], o[7]));
        *reinterpret_cast<uint4*>(&A_lds[p * 72 + h * 16 + half * 8]) = w4;
    }
    __syncthreads();

    const short* A_lds = reinterpret_cast<const short*>(smem);
    const int lane = t & 63;
    const int w    = t >> 6;                   // wave id
    const int mt   = w & 1;                    // M-tile (16 px)
    const int np2  = w >> 1;                   // N-pair (2 x 16 couts)
    const int l15  = lane & 15;
    const int kg4  = lane >> 4;

    bf16x8 afrag[2];
    #pragma unroll
    for (int ks = 0; ks < 2; ++ks)
        afrag[ks] = *reinterpret_cast<const bf16x8*>(
            &A_lds[(mt * 16 + l15) * 72 + ks * 32 + kg4 * 8]);

    #pragma unroll
    for (int nt2 = 0; nt2 < 2; ++nt2) {
        const int nt = np2 * 2 + nt2;
        const int n = nt * 16 + l15;
        f32x4 pacc = (f32x4){0.f, 0.f, 0.f, 0.f};
        #pragma unroll
        for (int ks = 0; ks < 2; ++ks) {
            bf16x8 b;
            #pragma unroll
            for (int e = 0; e < 8; ++e)
                b[e] = bf16s(wp[(ks * 32 + kg4 * 8 + e) * 64 + n]);
            pacc = __builtin_amdgcn_mfma_f32_16x16x32_bf16(afrag[ks], b, pacc, 0, 0, 0);
        }
        const int pr = mt * 16 + kg4 * 4;      // 4 consecutive tile pixels
        const int gy = Y0 + (pr >> 2);         // = one tile row
        *reinterpret_cast<float4*>(out + (size_t)n * NPIX + gy * WW + X0) =
            make_float4(pacc[0], pacc[1], pacc[2], pacc[3]);
    }
}

// ---------------------------------------------------------------------------
extern "C" void kernel_launch(void* const* d_in, const int* in_sizes, int n_in,
                              void* d_out, int out_size, void* d_ws, size_t ws_size,
                              hipStream_t stream)
{
    const float* x    = (const float*)d_in[0];
    const float* sims = (const float*)d_in[1];
    const float* wq   = (const float*)d_in[2];
    const float* wk   = (const float*)d_in[3];
    const float* wv   = (const float*)d_in[4];
    const float* wp   = (const float*)d_in[5];
    float* out = (float*)d_out;

    unsigned int* qg = (unsigned int*)d_ws;            // bf16x2 [NPIX][32]
    unsigned int* kg = qg + (size_t)NPIX * 32;
    unsigned int* vg = kg + (size_t)NPIX * 32;

    qkv_mfma<<<NPIX / 64, 256, 0, stream>>>(x, wq, wk, wv, qg, kg, vg);
    attn_proj<<<1152, 256, 0, stream>>>(qg, kg, vg, sims, wp, out);
}